// Round 11
// baseline (137.048 us; speedup 1.0000x reference)
//
#include <hip/hip_runtime.h>
#include <hip/hip_bf16.h>

#define NUM_OPS 8
#define D 1024
#define B_ROWS 8192

typedef unsigned short ushort_t;
typedef __attribute__((ext_vector_type(8))) short bf16x8;
typedef __attribute__((ext_vector_type(4))) float f32x4;
typedef __attribute__((ext_vector_type(4))) float float4v;
typedef __attribute__((ext_vector_type(8))) unsigned short ushort8;

__device__ __forceinline__ unsigned short f2bf(float f) {
    union { float f; unsigned int u; } v; v.f = f;
    unsigned int u = v.u;
    unsigned int lsb = (u >> 16) & 1u;
    u += 0x7fffu + lsb;   // round-to-nearest-even
    return (unsigned short)(u >> 16);
}

__device__ __forceinline__ void load_lds16(const void* g, void* l) {
    __builtin_amdgcn_global_load_lds(
        (const __attribute__((address_space(1))) void*)g,
        (__attribute__((address_space(3))) void*)l,
        16, 0, 0);
}

// deterministic top-2 (matches jax top_k tie-breaking: earliest index wins)
__device__ __forceinline__ void top2(const float* __restrict__ logits, int& i0, int& i1) {
    float best = -__builtin_inff(); i0 = 0;
    for (int i = 0; i < NUM_OPS; ++i) { float v = logits[i]; if (v > best) { best = v; i0 = i; } }
    float best2 = -__builtin_inff(); i1 = 0;
    for (int i = 0; i < NUM_OPS; ++i) {
        if (i == i0) continue;
        float v = logits[i]; if (v > best2) { best2 = v; i1 = i; }
    }
}

// ---------------- x : f32 -> bf16 (linear row-major) ----------------
__global__ void convert_x(const float* __restrict__ x, ushort_t* __restrict__ xb) {
    int i = (blockIdx.x * 256 + threadIdx.x) * 8;
    float4v v0 = *(const float4v*)(x + i);
    float4v v1 = *(const float4v*)(x + i + 4);
    ushort8 o;
    o[0] = f2bf(v0[0]); o[1] = f2bf(v0[1]); o[2] = f2bf(v0[2]); o[3] = f2bf(v0[3]);
    o[4] = f2bf(v1[0]); o[5] = f2bf(v1[1]); o[6] = f2bf(v1[2]); o[7] = f2bf(v1[3]);
    *(ushort8*)(xb + i) = o;
}

// ------- gather selected experts' W, transpose to [n][k], cast bf16 -------
__global__ void gather_transpose_W(const float* __restrict__ Ws,
                                   const float* __restrict__ logits,
                                   ushort_t* __restrict__ Wt) {
    __shared__ float t[32][33];
    int i0, i1; top2(logits, i0, i1);
    int e    = blockIdx.x >> 10;
    int tile = blockIdx.x & 1023;
    int td = (tile >> 5) << 5;
    int te = (tile & 31) << 5;
    int tx = threadIdx.x & 31, ty = threadIdx.x >> 5;
    const float* W = Ws + (size_t)(e ? i1 : i0) * D * D;
    for (int r = 0; r < 4; ++r)
        t[ty + 8 * r][tx] = W[(size_t)(td + ty + 8 * r) * D + te + tx];
    __syncthreads();
    ushort_t* o = Wt + (size_t)e * D * D;
    for (int r = 0; r < 4; ++r)
        o[(size_t)(te + ty + 8 * r) * D + td + tx] = f2bf(t[tx][ty + 8 * r]);
}

// -------- staging: linear LDS dest, inverse-XOR-swizzled global source -----
__device__ __forceinline__ void stageA(const ushort_t* __restrict__ xbf, int brow,
                                       int u, ushort_t* dst, int tid) {
    #pragma unroll
    for (int q = 0; q < 4; ++q) {                       // 256 rows x 128B = 32KB
        const int c   = q * 512 + tid;
        const int rr  = c >> 3;
        const int gcb = ((c & 7) * 16) ^ ((rr & 7) << 4);
        load_lds16(xbf + (size_t)(brow + rr) * D + u * 64 + (gcb >> 1), dst + c * 8);
    }
}
__device__ __forceinline__ void stageB(const ushort_t* __restrict__ Wt, int bcol,
                                       int u, ushort_t* dst, int tid) {
    #pragma unroll
    for (int q = 0; q < 2; ++q) {                       // 2e x 64 rows x 128B = 16KB
        const int c   = q * 512 + tid;
        const int e   = c >> 9, cc = c & 511;
        const int n   = cc >> 3;
        const int gcb = ((cc & 7) * 16) ^ ((n & 7) << 4);
        load_lds16(Wt + (size_t)e * D * D + (size_t)(bcol + n) * D + u * 64 + (gcb >> 1),
                   dst + c * 8);
    }
}

#define SB()    __builtin_amdgcn_sched_barrier(0)
#define PRIO1() __builtin_amdgcn_s_setprio(1)
#define PRIO0() __builtin_amdgcn_s_setprio(0)
#define VMN(N)  do { asm volatile("s_waitcnt vmcnt(" #N ")" ::: "memory"); } while (0)

#define RD_AB(CA, CB)                                                              \
    do {                                                                           \
        _Pragma("unroll") for (int kk = 0; kk < 2; ++kk)                           \
        _Pragma("unroll") for (int m = 0; m < 4; ++m)                              \
            a[kk][m] = *(const bf16x8*)((const char*)(CA) +                        \
                (size_t)((rgrp * 64 + m * 16 + l15) * 128) + (kk ? x1 : x0));      \
        _Pragma("unroll") for (int e = 0; e < 2; ++e)                              \
        _Pragma("unroll") for (int kk = 0; kk < 2; ++kk)                           \
        _Pragma("unroll") for (int n16 = 0; n16 < 2; ++n16)                        \
            b[e][kk][n16] = *(const bf16x8*)((const char*)(CB) + e * 8192 +        \
                (size_t)((cgrp * 32 + n16 * 16 + l15) * 128) + (kk ? x1 : x0));    \
    } while (0)

#define MM32()                                                                     \
    do {                                                                           \
        PRIO1();                                                                   \
        _Pragma("unroll") for (int kk = 0; kk < 2; ++kk)                           \
        _Pragma("unroll") for (int e = 0; e < 2; ++e)                              \
        _Pragma("unroll") for (int m = 0; m < 4; ++m)                              \
        _Pragma("unroll") for (int n16 = 0; n16 < 2; ++n16)                        \
            acc[e][m][n16] = __builtin_amdgcn_mfma_f32_16x16x32_bf16(              \
                a[kk][m], b[e][kk][n16], acc[e][m][n16], 0, 0, 0);                 \
        PRIO0();                                                                   \
    } while (0)

#define TILE(CA, CB, DA, DB, SU, VN, DOSTG, DOBAR)                                 \
    do {                                                                           \
        if (DOSTG) { stageA(xbf, brow, (SU), DA, tid);                             \
                     stageB(Wt,  bcol, (SU), DB, tid); }                           \
        SB();                                                                      \
        bf16x8 a[2][4], b[2][2][2];                                                \
        RD_AB(CA, CB);                                                             \
        MM32();                                                                    \
        SB();                                                                      \
        VMN(VN);                                                                   \
        if (DOBAR) __builtin_amdgcn_s_barrier();                                   \
    } while (0)

// -------- production: r9 3-buffer rotation (known-pass) --------
__global__ __launch_bounds__(512, 2)
void gemm_dual(const ushort_t* __restrict__ xbf, const ushort_t* __restrict__ Wt,
               const float* __restrict__ bs, const float* __restrict__ logits,
               float* __restrict__ out) {
    __shared__ __align__(16) ushort_t As0[256 * 64], As1[256 * 64], As2[256 * 64];
    __shared__ __align__(16) ushort_t Bs0[2 * 64 * 64], Bs1[2 * 64 * 64], Bs2[2 * 64 * 64];

    const int tid  = threadIdx.x;
    const int wv   = tid >> 6;
    const int lane = tid & 63;
    const int rgrp = wv >> 1, cgrp = wv & 1;
    const int l15  = lane & 15, lq = lane >> 4;
    const int swz  = (l15 & 7) << 4;
    const int x0   = (lq * 16) ^ swz;
    const int x1   = (64 + lq * 16) ^ swz;

    const int bid  = blockIdx.x;
    const int brow = (bid & 31) * 256;
    const int bcol = (bid >> 5) * 64;

    f32x4 acc[2][4][2] = {};

    stageA(xbf, brow, 0, As0, tid); stageB(Wt, bcol, 0, Bs0, tid);
    stageA(xbf, brow, 1, As1, tid); stageB(Wt, bcol, 1, Bs1, tid);
    SB();
    VMN(6);
    __builtin_amdgcn_s_barrier();

    TILE(As0, Bs0, As2, Bs2,  2, 6, true,  true);
    TILE(As1, Bs1, As0, Bs0,  3, 6, true,  true);
    TILE(As2, Bs2, As1, Bs1,  4, 6, true,  true);
    TILE(As0, Bs0, As2, Bs2,  5, 6, true,  true);
    TILE(As1, Bs1, As0, Bs0,  6, 6, true,  true);
    TILE(As2, Bs2, As1, Bs1,  7, 6, true,  true);
    TILE(As0, Bs0, As2, Bs2,  8, 6, true,  true);
    TILE(As1, Bs1, As0, Bs0,  9, 6, true,  true);
    TILE(As2, Bs2, As1, Bs1, 10, 6, true,  true);
    TILE(As0, Bs0, As2, Bs2, 11, 6, true,  true);
    TILE(As1, Bs1, As0, Bs0, 12, 6, true,  true);
    TILE(As2, Bs2, As1, Bs1, 13, 6, true,  true);
    TILE(As0, Bs0, As2, Bs2, 14, 6, true,  true);
    TILE(As1, Bs1, As0, Bs0, 15, 6, true,  true);
    TILE(As2, Bs2, As0, Bs0,  0, 0, false, true);
    TILE(As0, Bs0, As1, Bs1,  0, 0, false, false);

    int i0, i1; top2(logits, i0, i1);
    #pragma unroll
    for (int n16 = 0; n16 < 2; ++n16) {
        const int col = bcol + cgrp * 32 + n16 * 16 + l15;
        const float b0 = bs[i0 * D + col];
        const float b1 = bs[i1 * D + col];
        #pragma unroll
        for (int m = 0; m < 4; ++m) {
            const int rbase = brow + rgrp * 64 + m * 16 + lq * 4;
            #pragma unroll
            for (int i = 0; i < 4; ++i) {
                float v0 = acc[0][m][n16][i] + b0; v0 = v0 > 0.f ? v0 : 0.f;
                float v1 = acc[1][m][n16][i] + b1; v1 = v1 > 0.f ? v1 : 0.f;
                out[(size_t)(rbase + i) * D + col] = v0 + v1;
            }
        }
    }
}

// ================== ABLATION PROBES (diagnostic, scratch output) ============

// A: pure MFMA, zero memory. Healthy floor ~14us for this geometry.
__global__ __launch_bounds__(512, 2)
void abl_mfma(float* __restrict__ sink) {
    const int lane = threadIdx.x & 63;
    f32x4 acc[2][4][2] = {};
    bf16x8 a[2][4], b[2][2][2];
    #pragma unroll
    for (int kk = 0; kk < 2; ++kk)
        #pragma unroll
        for (int m = 0; m < 4; ++m)
            #pragma unroll
            for (int j = 0; j < 8; ++j)
                a[kk][m][j] = (short)(lane + kk * 7 + m * 3 + j);
    #pragma unroll
    for (int e = 0; e < 2; ++e)
        #pragma unroll
        for (int kk = 0; kk < 2; ++kk)
            #pragma unroll
            for (int n16 = 0; n16 < 2; ++n16)
                #pragma unroll
                for (int j = 0; j < 8; ++j)
                    b[e][kk][n16][j] = (short)((lane * 2) ^ (e * 5 + kk * 3 + n16 * 9 + j));
    #pragma unroll 1
    for (int it = 0; it < 16; ++it) { MM32(); }
    float s = 0.f;
    #pragma unroll
    for (int e = 0; e < 2; ++e)
        #pragma unroll
        for (int m = 0; m < 4; ++m)
            #pragma unroll
            for (int n = 0; n < 2; ++n)
                #pragma unroll
                for (int i = 0; i < 4; ++i) s += acc[e][m][n][i];
    sink[blockIdx.x * 512 + threadIdx.x] = s;
}

// B: LDS reads + MFMA (no VMEM, no barrier in loop).
__global__ __launch_bounds__(512, 2)
void abl_ds(float* __restrict__ sink) {
    __shared__ __align__(16) ushort_t As0[256 * 64], As1[256 * 64], As2[256 * 64];
    __shared__ __align__(16) ushort_t Bs0[2 * 64 * 64], Bs1[2 * 64 * 64], Bs2[2 * 64 * 64];
    const int tid = threadIdx.x;
    for (int i = tid; i < 256 * 64; i += 512) { As0[i] = (ushort_t)i; As1[i] = (ushort_t)(i + 1); As2[i] = (ushort_t)(i + 2); }
    for (int i = tid; i < 2 * 64 * 64; i += 512) { Bs0[i] = (ushort_t)i; Bs1[i] = (ushort_t)(i + 3); Bs2[i] = (ushort_t)(i + 5); }
    __syncthreads();
    const int wv = tid >> 6, lane = tid & 63;
    const int rgrp = wv >> 1, cgrp = wv & 1;
    const int l15 = lane & 15, lq = lane >> 4;
    const int swz = (l15 & 7) << 4;
    const int x0 = (lq * 16) ^ swz, x1 = (64 + lq * 16) ^ swz;
    f32x4 acc[2][4][2] = {};
    #pragma unroll 1
    for (int it = 0; it < 16; ++it) {
        const int c3 = it % 3;
        const char* cA = c3 == 0 ? (const char*)As0 : c3 == 1 ? (const char*)As1 : (const char*)As2;
        const char* cB = c3 == 0 ? (const char*)Bs0 : c3 == 1 ? (const char*)Bs1 : (const char*)Bs2;
        bf16x8 a[2][4], b[2][2][2];
        RD_AB(cA, cB);
        MM32();
    }
    float s = 0.f;
    #pragma unroll
    for (int e = 0; e < 2; ++e)
        #pragma unroll
        for (int m = 0; m < 4; ++m)
            #pragma unroll
            for (int n = 0; n < 2; ++n)
                #pragma unroll
                for (int i = 0; i < 4; ++i) s += acc[e][m][n][i];
    sink[blockIdx.x * 512 + threadIdx.x] = s;
}

// C: full pipeline minus s_barrier (stage + counted vmcnt + LDS reads + MFMA).
__global__ __launch_bounds__(512, 2)
void abl_stage(const ushort_t* __restrict__ xbf, const ushort_t* __restrict__ Wt,
               float* __restrict__ sink) {
    __shared__ __align__(16) ushort_t As0[256 * 64], As1[256 * 64], As2[256 * 64];
    __shared__ __align__(16) ushort_t Bs0[2 * 64 * 64], Bs1[2 * 64 * 64], Bs2[2 * 64 * 64];
    const int tid = threadIdx.x;
    const int wv = tid >> 6, lane = tid & 63;
    const int rgrp = wv >> 1, cgrp = wv & 1;
    const int l15 = lane & 15, lq = lane >> 4;
    const int swz = (l15 & 7) << 4;
    const int x0 = (lq * 16) ^ swz, x1 = (64 + lq * 16) ^ swz;
    const int bid = blockIdx.x;
    const int brow = (bid & 31) * 256, bcol = (bid >> 5) * 64;
    f32x4 acc[2][4][2] = {};
    stageA(xbf, brow, 0, As0, tid); stageB(Wt, bcol, 0, Bs0, tid);
    stageA(xbf, brow, 1, As1, tid); stageB(Wt, bcol, 1, Bs1, tid);
    SB(); VMN(6);
    #pragma unroll 1
    for (int it = 0; it < 16; ++it) {
        const int c3 = it % 3, s3 = (it + 2) % 3;
        const char* cA = c3 == 0 ? (const char*)As0 : c3 == 1 ? (const char*)As1 : (const char*)As2;
        const char* cB = c3 == 0 ? (const char*)Bs0 : c3 == 1 ? (const char*)Bs1 : (const char*)Bs2;
        ushort_t* dA = s3 == 0 ? As0 : s3 == 1 ? As1 : As2;
        ushort_t* dB = s3 == 0 ? Bs0 : s3 == 1 ? Bs1 : Bs2;
        if (it < 14) { stageA(xbf, brow, it + 2, dA, tid); stageB(Wt, bcol, it + 2, dB, tid); }
        SB();
        bf16x8 a[2][4], b[2][2][2];
        RD_AB(cA, cB);
        MM32();
        SB();
        VMN(6);
    }
    float s = 0.f;
    #pragma unroll
    for (int e = 0; e < 2; ++e)
        #pragma unroll
        for (int m = 0; m < 4; ++m)
            #pragma unroll
            for (int n = 0; n < 2; ++n)
                #pragma unroll
                for (int i = 0; i < 4; ++i) s += acc[e][m][n][i];
    sink[blockIdx.x * 512 + threadIdx.x] = s;
}

// D: the staging VMEM address stream alone (same addresses, reg loads).
__global__ __launch_bounds__(512, 2)
void abl_vmem(const ushort_t* __restrict__ xbf, const ushort_t* __restrict__ Wt,
              float* __restrict__ sink) {
    const int tid = threadIdx.x, bid = blockIdx.x;
    const int brow = (bid & 31) * 256, bcol = (bid >> 5) * 64;
    ushort8 av = {};
    #pragma unroll 1
    for (int u = 0; u < 16; ++u) {
        #pragma unroll
        for (int q = 0; q < 4; ++q) {
            const int c = q * 512 + tid, rr = c >> 3;
            const int gcb = ((c & 7) * 16) ^ ((rr & 7) << 4);
            av ^= *(const ushort8*)(xbf + (size_t)(brow + rr) * D + u * 64 + (gcb >> 1));
        }
        #pragma unroll
        for (int q = 0; q < 2; ++q) {
            const int c = q * 512 + tid, e = c >> 9, cc = c & 511, n = cc >> 3;
            const int gcb = ((cc & 7) * 16) ^ ((n & 7) << 4);
            av ^= *(const ushort8*)(Wt + (size_t)e * D * D + (size_t)(bcol + n) * D + u * 64 + (gcb >> 1));
        }
    }
    float s = 0.f;
    #pragma unroll
    for (int j = 0; j < 8; ++j) s += (float)av[j];
    sink[bid * 512 + tid] = s;
}

extern "C" void kernel_launch(void* const* d_in, const int* in_sizes, int n_in,
                              void* d_out, int out_size, void* d_ws, size_t ws_size,
                              hipStream_t stream) {
    const float* x      = (const float*)d_in[0];
    const float* logits = (const float*)d_in[1];
    const float* Ws     = (const float*)d_in[2];
    const float* bs     = (const float*)d_in[3];
    float* out = (float*)d_out;

    char* ws = (char*)d_ws;
    ushort_t* xbf = (ushort_t*)ws;                                   // 16 MB
    ushort_t* Wt  = (ushort_t*)(ws + (size_t)B_ROWS * D * 2);        //  4 MB
    float* sink0  = (float*)(ws + 20u * 1024 * 1024);
    float* sink1  = sink0 + (1 << 18);
    float* sink2  = sink1 + (1 << 18);
    float* sink3  = sink2 + (1 << 18);

    convert_x<<<(B_ROWS * D) / (256 * 8), 256, 0, stream>>>(x, xbf);
    gather_transpose_W<<<2 * (D / 32) * (D / 32), 256, 0, stream>>>(Ws, logits, Wt);

    gemm_dual<<<512, 512, 0, stream>>>(xbf, Wt, bs, logits, out);

    // diagnostics (scratch-only)
    abl_mfma <<<512, 512, 0, stream>>>(sink0);
    abl_ds   <<<512, 512, 0, stream>>>(sink1);
    abl_stage<<<512, 512, 0, stream>>>(xbf, Wt, sink2);
    abl_vmem <<<512, 512, 0, stream>>>(xbf, Wt, sink3);
}

// Round 12
// 57.757 us; speedup vs baseline: 2.3728x; 2.3728x over previous
//
#include <hip/hip_runtime.h>
#include <hip/hip_bf16.h>

#define NUM_OPS 8
#define D 1024
#define B_ROWS 8192

typedef unsigned short ushort_t;
typedef __attribute__((ext_vector_type(8))) short bf16x8;
typedef __attribute__((ext_vector_type(4))) float f32x4;
typedef __attribute__((ext_vector_type(4))) float float4v;
typedef __attribute__((ext_vector_type(8))) unsigned short ushort8;

__device__ __forceinline__ unsigned short f2bf(float f) {
    union { float f; unsigned int u; } v; v.f = f;
    unsigned int u = v.u;
    unsigned int lsb = (u >> 16) & 1u;
    u += 0x7fffu + lsb;   // round-to-nearest-even
    return (unsigned short)(u >> 16);
}

__device__ __forceinline__ void load_lds16(const void* g, void* l) {
    __builtin_amdgcn_global_load_lds(
        (const __attribute__((address_space(1))) void*)g,
        (__attribute__((address_space(3))) void*)l,
        16, 0, 0);
}

// deterministic top-2 (matches jax top_k tie-breaking: earliest index wins)
__device__ __forceinline__ void top2(const float* __restrict__ logits, int& i0, int& i1) {
    float best = -__builtin_inff(); i0 = 0;
    for (int i = 0; i < NUM_OPS; ++i) { float v = logits[i]; if (v > best) { best = v; i0 = i; } }
    float best2 = -__builtin_inff(); i1 = 0;
    for (int i = 0; i < NUM_OPS; ++i) {
        if (i == i0) continue;
        float v = logits[i]; if (v > best2) { best2 = v; i1 = i; }
    }
}

// ---------------- x : f32 -> bf16 (linear row-major) ----------------
__global__ void convert_x(const float* __restrict__ x, ushort_t* __restrict__ xb) {
    int i = (blockIdx.x * 256 + threadIdx.x) * 8;
    float4v v0 = *(const float4v*)(x + i);
    float4v v1 = *(const float4v*)(x + i + 4);
    ushort8 o;
    o[0] = f2bf(v0[0]); o[1] = f2bf(v0[1]); o[2] = f2bf(v0[2]); o[3] = f2bf(v0[3]);
    o[4] = f2bf(v1[0]); o[5] = f2bf(v1[1]); o[6] = f2bf(v1[2]); o[7] = f2bf(v1[3]);
    *(ushort8*)(xb + i) = o;
}

// ------- gather selected experts' W, transpose to [n][k], cast bf16 -------
__global__ void gather_transpose_W(const float* __restrict__ Ws,
                                   const float* __restrict__ logits,
                                   ushort_t* __restrict__ Wt) {
    __shared__ float t[32][33];
    int i0, i1; top2(logits, i0, i1);
    int e    = blockIdx.x >> 10;
    int tile = blockIdx.x & 1023;
    int td = (tile >> 5) << 5;
    int te = (tile & 31) << 5;
    int tx = threadIdx.x & 31, ty = threadIdx.x >> 5;
    const float* W = Ws + (size_t)(e ? i1 : i0) * D * D;
    for (int r = 0; r < 4; ++r)
        t[ty + 8 * r][tx] = W[(size_t)(td + ty + 8 * r) * D + te + tx];
    __syncthreads();
    ushort_t* o = Wt + (size_t)e * D * D;
    for (int r = 0; r < 4; ++r)
        o[(size_t)(te + ty + 8 * r) * D + td + tx] = f2bf(t[tx][ty + 8 * r]);
}

// -------- staging: linear LDS dest, inverse-XOR-swizzled global source -----
// LDS tile [256 rows][64 cols] bf16 (32KB); byte (r*128+c') holds global
// col-byte (c' ^ ((r&7)<<4)). 4 loads/thread at 512 threads.
__device__ __forceinline__ void stageA(const ushort_t* __restrict__ xbf, int brow,
                                       int u, ushort_t* dst, int tid) {
    #pragma unroll
    for (int q = 0; q < 4; ++q) {
        const int c   = q * 512 + tid;
        const int rr  = c >> 3;
        const int gcb = ((c & 7) * 16) ^ ((rr & 7) << 4);
        load_lds16(xbf + (size_t)(brow + rr) * D + u * 64 + (gcb >> 1), dst + c * 8);
    }
}
// B tile: rows = e*128 + col (256 rows of 64k = 32KB), same swizzle
__device__ __forceinline__ void stageB(const ushort_t* __restrict__ Wt, int bcol,
                                       int u, ushort_t* dst, int tid) {
    #pragma unroll
    for (int q = 0; q < 4; ++q) {
        const int c   = q * 512 + tid;
        const int rr  = c >> 3;
        const int e   = rr >> 7, n = rr & 127;
        const int gcb = ((c & 7) * 16) ^ ((rr & 7) << 4);
        load_lds16(Wt + (size_t)e * D * D + (size_t)(bcol + n) * D + u * 64 + (gcb >> 1),
                   dst + c * 8);
    }
}

#define SB()    __builtin_amdgcn_sched_barrier(0)
#define PRIO1() __builtin_amdgcn_s_setprio(1)
#define PRIO0() __builtin_amdgcn_s_setprio(0)
#define VMN(N)  do { asm volatile("s_waitcnt vmcnt(" #N ")" ::: "memory"); SB(); } while (0)

// 16 MFMA: expert E, K-half KK, b-array BB
#define MM16(E, KK, BB)                                                            \
    do {                                                                           \
        _Pragma("unroll") for (int m = 0; m < 4; ++m)                              \
        _Pragma("unroll") for (int n = 0; n < 4; ++n)                              \
            acc[E][m][n] = __builtin_amdgcn_mfma_f32_16x16x32_bf16(                \
                a[KK][m], BB[KK][n], acc[E][m][n], 0, 0, 0);                       \
    } while (0)

// one K-tile. Reads A(u) from CA, B(u) from CB; stages B(u+1)->DB, A(u+2)->DA.
// Trailing counted vmcnt keeps A-stage in flight across the raw barrier.
#define TILE(CA, CB, DB, DA, SUB, SUA, STGB, STGA, VN, DOBAR)                      \
    do {                                                                           \
        bf16x8 a[2][4], b0[2][4], b1[2][4];                                        \
        _Pragma("unroll") for (int kk = 0; kk < 2; ++kk)                           \
        _Pragma("unroll") for (int m = 0; m < 4; ++m)                              \
            a[kk][m] = *(const bf16x8*)((const char*)(CA) +                        \
                (size_t)((wr * 64 + m * 16 + l15) * 128) + (kk ? x1 : x0));        \
        _Pragma("unroll") for (int kk = 0; kk < 2; ++kk)                           \
        _Pragma("unroll") for (int n = 0; n < 4; ++n)                              \
            b0[kk][n] = *(const bf16x8*)((const char*)(CB) +                       \
                (size_t)((wc * 64 + n * 16 + l15) * 128) + (kk ? x1 : x0));        \
        if (STGB) stageB(Wt,  bcol, (SUB), DB, tid);                               \
        if (STGA) stageA(xbf, brow, (SUA), DA, tid);                               \
        SB();                                                                      \
        PRIO1(); MM16(0, 0, b0); PRIO0();                                          \
        _Pragma("unroll") for (int kk = 0; kk < 2; ++kk)                           \
        _Pragma("unroll") for (int n = 0; n < 4; ++n)                              \
            b1[kk][n] = *(const bf16x8*)((const char*)(CB) + 16384 +               \
                (size_t)((wc * 64 + n * 16 + l15) * 128) + (kk ? x1 : x0));        \
        PRIO1(); MM16(0, 1, b0); MM16(1, 0, b1); MM16(1, 1, b1); PRIO0();          \
        SB();                                                                      \
        VMN(VN);                                                                   \
        if (DOBAR) { __builtin_amdgcn_s_barrier(); SB(); }                         \
    } while (0)

// -------- fused dual-expert GEMM: high-intensity (42.7 FLOP/B) --------------
// Block: 256 rows x 128 cols x 2 experts, 8 waves (4M x 2N). Wave tile:
// 64r x 64c x 2e -> acc[2][4][4] = 128 VGPR. A loaded once per wave per tile,
// used by BOTH experts' B. LDS = A 3-buf (96KB) + B 2-buf (64KB) = 160KB.
// A(u+2) staged 2 tiles early, B(u+1) 1 tile early; trailing vmcnt(4).
__global__ __launch_bounds__(512, 2)
void gemm_dual(const ushort_t* __restrict__ xbf, const ushort_t* __restrict__ Wt,
               const float* __restrict__ bs, const float* __restrict__ logits,
               float* __restrict__ out) {
    __shared__ __align__(16) ushort_t As0[256 * 64], As1[256 * 64], As2[256 * 64];
    __shared__ __align__(16) ushort_t Bs0[256 * 64], Bs1[256 * 64];

    const int tid  = threadIdx.x;
    const int wv   = tid >> 6;
    const int lane = tid & 63;
    const int wr   = wv >> 1, wc = wv & 1;
    const int l15  = lane & 15, lq = lane >> 4;
    const int swz  = (l15 & 7) << 4;
    const int x0   = (lq * 16) ^ swz;
    const int x1   = (64 + lq * 16) ^ swz;

    // rows vary fastest across bids -> XCD x owns row-panels {x, x+8, ...}
    const int bid  = blockIdx.x;
    const int brow = (bid & 31) * 256;
    const int bcol = (bid >> 5) * 128;

    f32x4 acc[2][4][4] = {};

    // prologue: B(0), A(0), A(1); wait B0+A0 (A1 in flight)
    stageB(Wt,  bcol, 0, Bs0, tid);
    stageA(xbf, brow, 0, As0, tid);
    stageA(xbf, brow, 1, As1, tid);
    SB();
    VMN(4);
    __builtin_amdgcn_s_barrier(); SB();

    //    CA   CB   DB   DA   SUB SUA  STGB  STGA  VN  BAR
    TILE(As0, Bs0, Bs1, As2,  1,  2, true,  true,  4, true);   // u=0
    TILE(As1, Bs1, Bs0, As0,  2,  3, true,  true,  4, true);   // u=1
    TILE(As2, Bs0, Bs1, As1,  3,  4, true,  true,  4, true);   // u=2
    TILE(As0, Bs1, Bs0, As2,  4,  5, true,  true,  4, true);   // u=3
    TILE(As1, Bs0, Bs1, As0,  5,  6, true,  true,  4, true);   // u=4
    TILE(As2, Bs1, Bs0, As1,  6,  7, true,  true,  4, true);   // u=5
    TILE(As0, Bs0, Bs1, As2,  7,  8, true,  true,  4, true);   // u=6
    TILE(As1, Bs1, Bs0, As0,  8,  9, true,  true,  4, true);   // u=7
    TILE(As2, Bs0, Bs1, As1,  9, 10, true,  true,  4, true);   // u=8
    TILE(As0, Bs1, Bs0, As2, 10, 11, true,  true,  4, true);   // u=9
    TILE(As1, Bs0, Bs1, As0, 11, 12, true,  true,  4, true);   // u=10
    TILE(As2, Bs1, Bs0, As1, 12, 13, true,  true,  4, true);   // u=11
    TILE(As0, Bs0, Bs1, As2, 13, 14, true,  true,  4, true);   // u=12
    TILE(As1, Bs1, Bs0, As0, 14, 15, true,  true,  4, true);   // u=13
    TILE(As2, Bs0, Bs1, As1, 15,  0, true,  false, 0, true);   // u=14 (drain)
    TILE(As0, Bs1, Bs0, As1,  0,  0, false, false, 0, false);  // u=15

    // ---- epilogue: per-expert bias + relu, sum, store f32
    int i0, i1; top2(logits, i0, i1);
    #pragma unroll
    for (int n = 0; n < 4; ++n) {
        const int col = bcol + wc * 64 + n * 16 + l15;
        const float b0 = bs[i0 * D + col];
        const float b1 = bs[i1 * D + col];
        #pragma unroll
        for (int m = 0; m < 4; ++m) {
            const int rbase = brow + wr * 64 + m * 16 + lq * 4;
            #pragma unroll
            for (int i = 0; i < 4; ++i) {
                float v0 = acc[0][m][n][i] + b0; v0 = v0 > 0.f ? v0 : 0.f;
                float v1 = acc[1][m][n][i] + b1; v1 = v1 > 0.f ? v1 : 0.f;
                out[(size_t)(rbase + i) * D + col] = v0 + v1;
            }
        }
    }
}

extern "C" void kernel_launch(void* const* d_in, const int* in_sizes, int n_in,
                              void* d_out, int out_size, void* d_ws, size_t ws_size,
                              hipStream_t stream) {
    const float* x      = (const float*)d_in[0];
    const float* logits = (const float*)d_in[1];
    const float* Ws     = (const float*)d_in[2];
    const float* bs     = (const float*)d_in[3];
    float* out = (float*)d_out;

    char* ws = (char*)d_ws;
    ushort_t* xbf = (ushort_t*)ws;                                   // 16 MB
    ushort_t* Wt  = (ushort_t*)(ws + (size_t)B_ROWS * D * 2);        //  4 MB

    convert_x<<<(B_ROWS * D) / (256 * 8), 256, 0, stream>>>(x, xbf);
    gather_transpose_W<<<2 * (D / 32) * (D / 32), 256, 0, stream>>>(Ws, logits, Wt);

    gemm_dual<<<256, 512, 0, stream>>>(xbf, Wt, bs, logits, out);
}

// Round 13
// 52.023 us; speedup vs baseline: 2.6344x; 1.1102x over previous
//
#include <hip/hip_runtime.h>
#include <hip/hip_bf16.h>

#define NUM_OPS 8
#define D 1024
#define B_ROWS 8192

typedef unsigned short ushort_t;
typedef __attribute__((ext_vector_type(8))) short bf16x8;
typedef __attribute__((ext_vector_type(4))) float f32x4;
typedef __attribute__((ext_vector_type(4))) float float4v;
typedef __attribute__((ext_vector_type(8))) unsigned short ushort8;

__device__ __forceinline__ unsigned short f2bf(float f) {
    union { float f; unsigned int u; } v; v.f = f;
    unsigned int u = v.u;
    unsigned int lsb = (u >> 16) & 1u;
    u += 0x7fffu + lsb;   // round-to-nearest-even
    return (unsigned short)(u >> 16);
}

__device__ __forceinline__ void load_lds16(const void* g, void* l) {
    __builtin_amdgcn_global_load_lds(
        (const __attribute__((address_space(1))) void*)g,
        (__attribute__((address_space(3))) void*)l,
        16, 0, 0);
}

// deterministic top-2 (matches jax top_k tie-breaking: earliest index wins)
__device__ __forceinline__ void top2(const float* __restrict__ logits, int& i0, int& i1) {
    float best = -__builtin_inff(); i0 = 0;
    for (int i = 0; i < NUM_OPS; ++i) { float v = logits[i]; if (v > best) { best = v; i0 = i; } }
    float best2 = -__builtin_inff(); i1 = 0;
    for (int i = 0; i < NUM_OPS; ++i) {
        if (i == i0) continue;
        float v = logits[i]; if (v > best2) { best2 = v; i1 = i; }
    }
}

// ---------------- x : f32 -> bf16 (linear row-major) ----------------
__global__ void convert_x(const float* __restrict__ x, ushort_t* __restrict__ xb) {
    int i = (blockIdx.x * 256 + threadIdx.x) * 8;
    float4v v0 = *(const float4v*)(x + i);
    float4v v1 = *(const float4v*)(x + i + 4);
    ushort8 o;
    o[0] = f2bf(v0[0]); o[1] = f2bf(v0[1]); o[2] = f2bf(v0[2]); o[3] = f2bf(v0[3]);
    o[4] = f2bf(v1[0]); o[5] = f2bf(v1[1]); o[6] = f2bf(v1[2]); o[7] = f2bf(v1[3]);
    *(ushort8*)(xb + i) = o;
}

// ------- gather selected experts' W into MFMA B-fragment order (r6-verified)
// fi = (((e*32 + p)*16 + u)*2 + kk)*2 + n16 ; Wf[fi*512 + lane*8 + j] =
//   W_e[u*64 + kk*32 + (lane>>4)*8 + j][p*32 + n16*16 + (lane&15)]
__global__ void gather_frag_W(const float* __restrict__ Ws,
                              const float* __restrict__ logits,
                              ushort_t* __restrict__ Wf) {
    __shared__ float t[32][33];
    int s0, s1; top2(logits, s0, s1);
    const int b  = blockIdx.x;              // ((e*32 + kt)*32 + nt)
    const int nt = b & 31, kt = (b >> 5) & 31, e = b >> 10;
    const int td = kt * 32, te = nt * 32;
    const int tx = threadIdx.x & 31, ty = threadIdx.x >> 5;
    const float* W = Ws + (size_t)(e ? s1 : s0) * D * D;
    #pragma unroll
    for (int r = 0; r < 4; ++r)
        t[ty + 8 * r][tx] = W[(size_t)(td + ty + 8 * r) * D + te + tx];
    __syncthreads();
    const int vid = threadIdx.x;
    if (vid < 128) {
        const int n_l = vid & 31, kg = vid >> 5;
        const int n = te + n_l, k0 = td + kg * 8;
        const int u = k0 >> 6, kk = (k0 >> 5) & 1, lq = (k0 >> 3) & 3;
        const int p = n >> 5, n16 = (n >> 4) & 1, l15 = n & 15;
        const int lane = lq * 16 + l15;
        const int fi = (((e * 32 + p) * 16 + u) * 2 + kk) * 2 + n16;
        ushort8 o;
        #pragma unroll
        for (int j = 0; j < 8; ++j) o[j] = f2bf(t[kg * 8 + j][n_l]);
        *(ushort8*)(Wf + (size_t)fi * 512 + lane * 8) = o;
    }
}

// -------- A staging (r5-verified): linear LDS dest, inverse-swizzled source -
// LDS tile [128 rows][64 cols] bf16; byte (r*128+c') holds col (c'^((r&7)<<4)).
__device__ __forceinline__ void stageA128(const ushort_t* __restrict__ xbf,
                                          int brow, int u, ushort_t* dst,
                                          int tid, int wv) {
    #pragma unroll
    for (int it = 0; it < 4; ++it) {
        const int c   = it * 256 + tid;
        const int rr  = c >> 3;
        const int cb  = (c & 7) * 16;
        const int gcb = cb ^ ((rr & 7) << 4);
        const ushort_t* g = xbf + (size_t)(brow + rr) * D + u * 64 + (gcb >> 1);
        ushort_t* l = dst + (it * 256 + wv * 64) * 8;
        load_lds16(g, l);
    }
}

#define PRIO1() __builtin_amdgcn_s_setprio(1)
#define PRIO0() __builtin_amdgcn_s_setprio(0)

// one K-tile: stage A(u+1) -> load 16 B-frags (global, L2) -> read 8 A-frags
// (LDS) -> 64 MFMA (compiler inserts fine-grained waits) -> counted vmcnt(12)
// (stage loads are the 4 oldest of this tile's 20 VMEM ops -> provably
// retired) -> raw barrier. No vmcnt(0) in the loop.
#define TILE(CUR, NXT, U, STG, VN, DOBAR)                                          \
    do {                                                                           \
        if (STG) stageA128(xbf, brow, (U) + 1, NXT, tid, wv);                      \
        bf16x8 b[2][2][2][2];                                                      \
        _Pragma("unroll") for (int e = 0; e < 2; ++e)                              \
        _Pragma("unroll") for (int pp = 0; pp < 2; ++pp)                           \
        _Pragma("unroll") for (int kk = 0; kk < 2; ++kk)                           \
        _Pragma("unroll") for (int n16 = 0; n16 < 2; ++n16) {                      \
            const int fi = (((e * 32 + p0 + pp) * 16 + (U)) * 2 + kk) * 2 + n16;   \
            b[e][pp][kk][n16] = *(const bf16x8*)(Wf + (size_t)fi * 512 + lane * 8);\
        }                                                                          \
        bf16x8 a[2][4];                                                            \
        _Pragma("unroll") for (int kk = 0; kk < 2; ++kk)                           \
        _Pragma("unroll") for (int m = 0; m < 4; ++m)                              \
            a[kk][m] = *(const bf16x8*)((const char*)(CUR) +                       \
                (size_t)((wr * 64 + m * 16 + l15) * 128) + (kk ? x1 : x0));        \
        PRIO1();                                                                   \
        _Pragma("unroll") for (int kk = 0; kk < 2; ++kk)                           \
        _Pragma("unroll") for (int e = 0; e < 2; ++e)                              \
        _Pragma("unroll") for (int m = 0; m < 4; ++m)                              \
        _Pragma("unroll") for (int pp = 0; pp < 2; ++pp)                           \
        _Pragma("unroll") for (int n16 = 0; n16 < 2; ++n16)                        \
            acc[e][m][pp][n16] = __builtin_amdgcn_mfma_f32_16x16x32_bf16(          \
                a[kk][m], b[e][pp][kk][n16], acc[e][m][pp][n16], 0, 0, 0);         \
        PRIO0();                                                                   \
        asm volatile("s_waitcnt vmcnt(" #VN ")" ::: "memory");                     \
        if (DOBAR) __builtin_amdgcn_s_barrier();                                   \
    } while (0)

// -------- fused dual-expert GEMM: A-LDS / B-direct, 2 blocks/CU TLP ---------
// Block: 4 waves (2x2), tile 128r x 128c x 2e. Wave: 64r x 64c x 2e ->
// acc[2][4][2][2] = 128 VGPR (42.7 FLOP/B). A: LDS dbuf 2x16KB (swizzled,
// global_load_lds w16). B: frag-direct from Wf, L2-resident per XCD
// (bcol = (bid&7)*128 matches bid%8 XCD round-robin); wr-pairs share B in L1.
__global__ __launch_bounds__(256, 2)
void gemm_dual(const ushort_t* __restrict__ xbf, const ushort_t* __restrict__ Wf,
               const float* __restrict__ bs, const float* __restrict__ logits,
               float* __restrict__ out) {
    __shared__ __align__(16) ushort_t As0[128 * 64], As1[128 * 64];   // 32 KB

    const int tid  = threadIdx.x;
    const int wv   = tid >> 6;
    const int lane = tid & 63;
    const int wr   = wv >> 1, wc = wv & 1;
    const int l15  = lane & 15, lq = lane >> 4;
    const int swz  = (l15 & 7) << 4;
    const int x0   = (lq * 16) ^ swz;
    const int x1   = (64 + lq * 16) ^ swz;

    const int bid  = blockIdx.x;
    const int brow = (bid >> 3) * 128;        // 64 row-blocks per XCD stream
    const int bcol = (bid & 7) * 128;         // col-panel == XCD (bid%8)
    const int p0   = (bcol >> 5) + wc * 2;    // wave's first 32-col panel

    f32x4 acc[2][4][2][2] = {};

    // prologue: stage tile 0, full drain once, barrier
    stageA128(xbf, brow, 0, As0, tid, wv);
    asm volatile("s_waitcnt vmcnt(0)" ::: "memory");
    __builtin_amdgcn_s_barrier();

    TILE(As0, As1,  0, true, 12, true);
    TILE(As1, As0,  1, true, 12, true);
    TILE(As0, As1,  2, true, 12, true);
    TILE(As1, As0,  3, true, 12, true);
    TILE(As0, As1,  4, true, 12, true);
    TILE(As1, As0,  5, true, 12, true);
    TILE(As0, As1,  6, true, 12, true);
    TILE(As1, As0,  7, true, 12, true);
    TILE(As0, As1,  8, true, 12, true);
    TILE(As1, As0,  9, true, 12, true);
    TILE(As0, As1, 10, true, 12, true);
    TILE(As1, As0, 11, true, 12, true);
    TILE(As0, As1, 12, true, 12, true);
    TILE(As1, As0, 13, true, 12, true);
    TILE(As0, As1, 14, true, 12, true);
    TILE(As1, As0, 15, false, 0, false);

    // ---- epilogue: per-expert bias + relu, sum, store f32 (r6-verified map)
    int i0, i1; top2(logits, i0, i1);
    #pragma unroll
    for (int pp = 0; pp < 2; ++pp)
    #pragma unroll
    for (int n16 = 0; n16 < 2; ++n16) {
        const int col = bcol + wc * 64 + pp * 32 + n16 * 16 + l15;
        const float b0 = bs[i0 * D + col];
        const float b1 = bs[i1 * D + col];
        #pragma unroll
        for (int m = 0; m < 4; ++m) {
            const int rbase = brow + wr * 64 + m * 16 + lq * 4;
            #pragma unroll
            for (int i = 0; i < 4; ++i) {
                float v0 = acc[0][m][pp][n16][i] + b0; v0 = v0 > 0.f ? v0 : 0.f;
                float v1 = acc[1][m][pp][n16][i] + b1; v1 = v1 > 0.f ? v1 : 0.f;
                out[(size_t)(rbase + i) * D + col] = v0 + v1;
            }
        }
    }
}

extern "C" void kernel_launch(void* const* d_in, const int* in_sizes, int n_in,
                              void* d_out, int out_size, void* d_ws, size_t ws_size,
                              hipStream_t stream) {
    const float* x      = (const float*)d_in[0];
    const float* logits = (const float*)d_in[1];
    const float* Ws     = (const float*)d_in[2];
    const float* bs     = (const float*)d_in[3];
    float* out = (float*)d_out;

    char* ws = (char*)d_ws;
    ushort_t* xbf = (ushort_t*)ws;                                   // 16 MB
    ushort_t* Wf  = (ushort_t*)(ws + (size_t)B_ROWS * D * 2);        //  4 MB

    convert_x<<<(B_ROWS * D) / (256 * 8), 256, 0, stream>>>(x, xbf);
    gather_frag_W<<<2 * 32 * 32, 256, 0, stream>>>(Ws, logits, Wf);

    gemm_dual<<<512, 256, 0, stream>>>(xbf, Wf, bs, logits, out);
}